// Round 1
// baseline (209.848 us; speedup 1.0000x reference)
//
#include <hip/hip_runtime.h>

// YOLOv1 loss, fused single pass.
// pred, labels: [B=16384, C=30, G=7, G=7] fp32. Output: scalar fp32.
// One thread per (b, m, n) cell. 16384*49 = 802816 cells = 3136 * 256 exactly.

constexpr int BATCH = 16384;
constexpr int CH    = 30;
constexpr int G     = 7;
constexpr int GG    = G * G;               // 49
constexpr int CELLS = BATCH * GG;          // 802816
constexpr int TPB   = 256;
constexpr int NBLK  = CELLS / TPB;         // 3136 (exact)

__global__ void zero_out_kernel(float* __restrict__ out) {
    out[0] = 0.0f;
}

__device__ __forceinline__ float sq(float x) { return x * x; }

__global__ __launch_bounds__(TPB) void yolo_loss_kernel(
    const float* __restrict__ pred,
    const float* __restrict__ lab,
    float* __restrict__ out)
{
    const int tid  = blockIdx.x * TPB + threadIdx.x;
    const int b    = tid / GG;
    const int cell = tid - b * GG;
    const int m    = cell / G;         // grid index along dim -2
    const int n    = cell - m * G;     // grid index along dim -1

    const float* p = pred + (size_t)b * (CH * GG) + cell;
    const float* l = lab  + (size_t)b * (CH * GG) + cell;

    // Load pred ch 0..9, labels ch 0..8 (labels ch 9 unused by the reference).
    float pv[10];
#pragma unroll
    for (int c = 0; c < 10; ++c) pv[c] = p[c * GG];
    float lv[9];
#pragma unroll
    for (int c = 0; c < 9; ++c) lv[c] = l[c * GG];

    // Class term: channels 10..29.
    float cls = 0.0f;
#pragma unroll
    for (int c = 10; c < 30; ++c) {
        float d = p[c * GG] - l[c * GG];
        cls += d * d;
    }

    const float gx = (float)m;
    const float gy = (float)n;
    const float inv7 = 1.0f / 7.0f;

    // box1 (pred ch 0..3)
    const float cx1 = (pv[0] + gx) * inv7, cy1 = (pv[1] + gy) * inv7;
    const float hw1 = 0.5f * pv[2],        hh1 = 0.5f * pv[3];
    const float a1x1 = cx1 - hw1, a1y1 = cy1 - hh1, a1x2 = cx1 + hw1, a1y2 = cy1 + hh1;
    // box2 (pred ch 5..8)
    const float cx2 = (pv[5] + gx) * inv7, cy2 = (pv[6] + gy) * inv7;
    const float hw2 = 0.5f * pv[7],        hh2 = 0.5f * pv[8];
    const float a2x1 = cx2 - hw2, a2y1 = cy2 - hh2, a2x2 = cx2 + hw2, a2y2 = cy2 + hh2;
    // gt box (labels ch 0..3)
    const float cxg = (lv[0] + gx) * inv7, cyg = (lv[1] + gy) * inv7;
    const float hwg = 0.5f * lv[2],        hhg = 0.5f * lv[3];
    const float gx1 = cxg - hwg, gy1 = cyg - hhg, gx2 = cxg + hwg, gy2 = cyg + hhg;

    const float area_g = (gx2 - gx1) * (gy2 - gy1);

    // IOU(box1, gt)
    float ix1 = fmaxf(a1x1, gx1), iy1 = fmaxf(a1y1, gy1);
    float ix2 = fminf(a1x2, gx2), iy2 = fminf(a1y2, gy2);
    float inter1 = fmaxf(ix2 - ix1, 0.0f) * fmaxf(iy2 - iy1, 0.0f);
    float area1  = (a1x2 - a1x1) * (a1y2 - a1y1);
    float iou1 = (inter1 > 0.0f) ? inter1 / (area1 + area_g - inter1) : 0.0f;

    // IOU(box2, gt)
    ix1 = fmaxf(a2x1, gx1); iy1 = fmaxf(a2y1, gy1);
    ix2 = fminf(a2x2, gx2); iy2 = fminf(a2y2, gy2);
    float inter2 = fmaxf(ix2 - ix1, 0.0f) * fmaxf(iy2 - iy1, 0.0f);
    float area2  = (a2x2 - a2x1) * (a2y2 - a2y1);
    float iou2 = (inter2 > 0.0f) ? inter2 / (area2 + area_g - inter2) : 0.0f;

    const bool resp1 = iou1 > iou2;
    const float obj = (lv[4] == 1.0f) ? 1.0f : 0.0f;

    const float coor1 = sq(pv[0] - lv[0]) + sq(pv[1] - lv[1])
                      + sq(sqrtf(pv[2]) - sqrtf(lv[2])) + sq(sqrtf(pv[3]) - sqrtf(lv[3]));
    const float coor2 = sq(pv[5] - lv[5]) + sq(pv[6] - lv[6])
                      + sq(sqrtf(pv[7]) - sqrtf(lv[7])) + sq(sqrtf(pv[8]) - sqrtf(lv[8]));
    const float coor = resp1 ? coor1 : coor2;

    const float e1 = sq(pv[4] - iou1);
    const float e2 = sq(pv[9] - iou2);
    const float obj_conf   = resp1 ? e1 : e2;
    const float noobj_resp = resp1 ? e2 : e1;

    float cell_loss = obj * (5.0f * coor + obj_conf + 0.5f * noobj_resp + cls)
                    + (1.0f - obj) * 0.5f * (pv[4] * pv[4] + pv[9] * pv[9]);

    // ---- reduction: wave(64) shuffle -> LDS across 4 waves -> 1 atomic/block
    float v = cell_loss;
#pragma unroll
    for (int off = 32; off > 0; off >>= 1) v += __shfl_down(v, off, 64);

    __shared__ float wsum[TPB / 64];
    const int lane = threadIdx.x & 63;
    const int wid  = threadIdx.x >> 6;
    if (lane == 0) wsum[wid] = v;
    __syncthreads();
    if (threadIdx.x == 0) {
        float s = wsum[0] + wsum[1] + wsum[2] + wsum[3];
        // faithful reference quirk: divide by (N-1) == 6, not batch size
        atomicAdd(out, s * (1.0f / 6.0f));
    }
}

extern "C" void kernel_launch(void* const* d_in, const int* in_sizes, int n_in,
                              void* d_out, int out_size, void* d_ws, size_t ws_size,
                              hipStream_t stream) {
    const float* pred = (const float*)d_in[0];
    const float* lab  = (const float*)d_in[1];
    float* out = (float*)d_out;

    zero_out_kernel<<<1, 1, 0, stream>>>(out);
    yolo_loss_kernel<<<NBLK, TPB, 0, stream>>>(pred, lab, out);
}